// Round 7
// baseline (144.323 us; speedup 1.0000x reference)
//
#include <hip/hip_runtime.h>

#define IN_DIM   256
#define OUT_DIM  256
#define NKNOT    19
#define X_MIN_C  (-5.0f)
#define H_C      (10.0f / 19.0f)
#define INV_H_C  (19.0f / 10.0f)

#define ROWS     5                      // og entries per (i_l,k) row: 4 used + 1 pad (bank spread)
#define PLANE_E  (8 * NKNOT * ROWS)     // 760 uint4 per plane per slice
#define SLICE_E  (2 * PLANE_E)          // 1520 uint4 per (g, i_grp) slice (24,320 B)
// Ct layout: [g 16][i_grp 32][plane 2][i_l 8][k 19][row 5] of uint4 (bf16 pairs over 4 o's)

// pack two f32 -> bf16 pair (RNE): low = x, high = y
__device__ __forceinline__ unsigned int pk_bf16(float x, float y) {
    unsigned int ux = __float_as_uint(x); ux += 0x7FFFu + ((ux >> 16) & 1u);
    unsigned int uy = __float_as_uint(y); uy += 0x7FFFu + ((uy >> 16) & 1u);
    return (ux >> 16) | (uy & 0xFFFF0000u);
}
__device__ __forceinline__ float lo16(unsigned int u) { return __uint_as_float(u << 16); }
__device__ __forceinline__ float hi16(unsigned int u) { return __uint_as_float(u & 0xFFFF0000u); }

// ---------------------------------------------------------------------------
// K1: pack coeffs [o 256][i 256][k 19] float4 -> Ct slices.
// block = (g = o-group of 16, i). Stage 16x19 float4 in LDS, pack 152 entries.
// ---------------------------------------------------------------------------
__global__ __launch_bounds__(256) void pack_coeffs(
        const float4* __restrict__ src, uint4* __restrict__ dst) {
    __shared__ float4 buf[16 * NKNOT];       // [o_l 16][k 19]
    const int g = blockIdx.x & 15;
    const int i = blockIdx.x >> 4;

    for (int e = threadIdx.x; e < 16 * NKNOT; e += 256) {
        const int o_l = e / NKNOT, k = e - o_l * NKNOT;
        buf[e] = src[((size_t)(g * 16 + o_l) * IN_DIM + i) * NKNOT + k];
    }
    __syncthreads();

    const int t = threadIdx.x;
    if (t < 2 * 76) {
        const int plane = t / 76;
        const int r     = t - plane * 76;
        const int k = r >> 2, og = r & 3;
        const float4 v0 = buf[(og * 4 + 0) * NKNOT + k];
        const float4 v1 = buf[(og * 4 + 1) * NKNOT + k];
        const float4 v2 = buf[(og * 4 + 2) * NKNOT + k];
        const float4 v3 = buf[(og * 4 + 3) * NKNOT + k];
        uint4 w;
        if (plane == 0) {                    // AB: {a01,a23,b01,b23}
            w.x = pk_bf16(v0.x, v1.x); w.y = pk_bf16(v2.x, v3.x);
            w.z = pk_bf16(v0.y, v1.y); w.w = pk_bf16(v2.y, v3.y);
        } else {                             // CD: {c01,c23,d01,d23}
            w.x = pk_bf16(v0.z, v1.z); w.y = pk_bf16(v2.z, v3.z);
            w.z = pk_bf16(v0.w, v1.w); w.w = pk_bf16(v2.w, v3.w);
        }
        const int i_grp = i >> 3, i_l = i & 7;
        dst[(size_t)(g * 32 + i_grp) * SLICE_E + plane * PLANE_E
            + (i_l * NKNOT + k) * ROWS + og] = w;
    }
}

// ---------------------------------------------------------------------------
// K2: tk precompute. tkg layout [i_grp 32][b][i_l 8] int2 {k*ROWS, t bits}
// so K3's per-chunk stages are contiguous.
// ---------------------------------------------------------------------------
__global__ __launch_bounds__(256) void make_tk(
        const float* __restrict__ x, int2* __restrict__ tkg, int Btot) {
    const int n = blockIdx.x * 256 + threadIdx.x;
    if (n >= Btot * IN_DIM) return;
    const int b = n >> 8, i = n & 255;
    const float xv = x[n];
    int idx = (int)floorf((xv - X_MIN_C) * INV_H_C);
    idx = idx < 0 ? 0 : (idx > NKNOT - 1 ? NKNOT - 1 : idx);
    tkg[((size_t)(i >> 3) * Btot + b) * 8 + (i & 7)] =
        make_int2(idx * ROWS, __float_as_int(xv - (X_MIN_C + (float)idx * H_C)));
}

// ---------------------------------------------------------------------------
// K3: main. grid = 16 g x 32 i_grp x 2 bh = 1024 blocks (4/CU, 16 waves/CU).
// Stage 24KB coeff slice once; per chunk of 64 b: stage tk (bank-padded),
// then pure-LDS gather + Horner. Thread = (b_l 64, og 4): 4 o's, 8 i's/chunk.
// ---------------------------------------------------------------------------
__global__ __launch_bounds__(256, 4) void kan_main(
        const int2*  __restrict__ tkg,
        const uint4* __restrict__ Ct,
        float4*      __restrict__ part,    // [(i_grp*16+g)][b] float4[4] (og)
        int Btot) {
    __shared__ uint4 cs[SLICE_E];          // 24,320 B coeff slice
    __shared__ int2  stk[64 * 9];          // 64 b x 8 i, row-padded to 9

    const int g     = blockIdx.x & 15;
    const int i_grp = (blockIdx.x >> 4) & 31;
    const int bh    = blockIdx.x >> 9;
    const int tid   = threadIdx.x;

    const uint4* slice = Ct + (size_t)(g * 32 + i_grp) * SLICE_E;
    for (int e = tid; e < SLICE_E; e += 256) cs[e] = slice[e];

    const int b_l = tid >> 2;
    const int og  = tid & 3;
    const uint4* ab = cs + og;
    const uint4* cd = cs + PLANE_E + og;

    const int half    = Btot >> 1;
    const int nchunks = half >> 6;         // chunks of 64 b

    for (int c = 0; c < nchunks; ++c) {
        const int bbase = bh * half + c * 64;
        __syncthreads();                   // protect stk (and cs on c==0)
        {
            const size_t tb = ((size_t)i_grp * Btot + bbase) * 8;
            int e = tid;
            stk[(e >> 3) * 9 + (e & 7)] = tkg[tb + e];
            e += 256;
            stk[(e >> 3) * 9 + (e & 7)] = tkg[tb + e];
        }
        __syncthreads();

        float y0 = 0.f, y1 = 0.f, y2 = 0.f, y3 = 0.f;
        #pragma unroll
        for (int i = 0; i < 8; ++i) {
            const int2 tk = stk[b_l * 9 + i];
            const int  e  = i * (NKNOT * ROWS) + tk.x;   // (i*19 + k) * 5
            const uint4 AB = ab[e];
            const uint4 CD = cd[e];
            const float t  = __int_as_float(tk.y);
            const float a_0 = lo16(AB.x), a_1 = hi16(AB.x), a_2 = lo16(AB.y), a_3 = hi16(AB.y);
            const float b_0 = lo16(AB.z), b_1 = hi16(AB.z), b_2 = lo16(AB.w), b_3 = hi16(AB.w);
            const float c_0 = lo16(CD.x), c_1 = hi16(CD.x), c_2 = lo16(CD.y), c_3 = hi16(CD.y);
            const float d_0 = lo16(CD.z), d_1 = hi16(CD.z), d_2 = lo16(CD.w), d_3 = hi16(CD.w);
            y0 += ((d_0 * t + c_0) * t + b_0) * t + a_0;
            y1 += ((d_1 * t + c_1) * t + b_1) * t + a_1;
            y2 += ((d_2 * t + c_2) * t + b_2) * t + a_2;
            y3 += ((d_3 * t + c_3) * t + b_3) * t + a_3;
        }

        part[((size_t)(i_grp * 16 + g) * Btot + bbase + b_l) * 4 + og] =
            make_float4(y0, y1, y2, y3);
    }
}

// ---------------------------------------------------------------------------
// K4: out[b, o] = bias[o] + sum over 32 i_grp partials.
// n indexes (b, g, og) -> coalesced float4 writes.
// ---------------------------------------------------------------------------
__global__ __launch_bounds__(256) void kan_reduce(
        const float4* __restrict__ part,
        const float4* __restrict__ bias4,  // [64]
        float4*       __restrict__ out,
        int Btot) {
    const int n = blockIdx.x * 256 + threadIdx.x;
    if (n >= Btot * 64) return;
    const int b  = n >> 6;
    const int g  = (n >> 2) & 15;
    const int og = n & 3;
    float4 s = bias4[n & 63];
    #pragma unroll 8
    for (int i_grp = 0; i_grp < 32; ++i_grp) {
        const float4 p = part[((size_t)(i_grp * 16 + g) * Btot + b) * 4 + og];
        s.x += p.x; s.y += p.y; s.z += p.z; s.w += p.w;
    }
    out[n] = s;
}

// ---------------------------------------------------------------------------
extern "C" void kernel_launch(void* const* d_in, const int* in_sizes, int n_in,
                              void* d_out, int out_size, void* d_ws, size_t ws_size,
                              hipStream_t stream) {
    const float* x      = (const float*)d_in[0];   // (B, 256) fp32
    const float* coeffs = (const float*)d_in[1];   // (256, 256, 19, 4) fp32
    const float* bias   = (const float*)d_in[2];   // (256,) fp32
    float*       out    = (float*)d_out;           // (B, 256) fp32

    const int Btot = in_sizes[0] / IN_DIM;         // 1024
    uint4* Ct   = (uint4*)d_ws;                            // 16*32*1520*16B = 11.9 MB
    int2*  tkg  = (int2*)((char*)d_ws + (16u << 20));      // 2 MB
    float* part = (float*)((char*)d_ws + (32u << 20));     // 512*Btot*16B = 8 MB

    pack_coeffs<<<16 * IN_DIM, 256, 0, stream>>>((const float4*)coeffs, Ct);
    make_tk<<<(Btot * IN_DIM + 255) / 256, 256, 0, stream>>>(x, tkg, Btot);
    kan_main<<<1024, 256, 0, stream>>>(tkg, Ct, (float4*)part, Btot);
    kan_reduce<<<(Btot * 64 + 255) / 256, 256, 0, stream>>>(
        (const float4*)part, (const float4*)bias, (float4*)out, Btot);
}

// Round 9
// 99.905 us; speedup vs baseline: 1.4446x; 1.4446x over previous
//
#include <hip/hip_runtime.h>

#define IN_DIM   256
#define OUT_DIM  256
#define NKNOT    19                    // NUM_KNOTS-1 spline segments
#define NCOL     (IN_DIM * NKNOT)      // 4864 (i,k) columns
#define CPQ      1216                  // columns per i-quarter (64*19)
#define PLANE_U4 (CPQ * 32)            // 38912 uint4 per plane
#define SLICE_U4 (PLANE_U4 * 2)        // AB plane + CD plane
#define X_MIN_C  (-5.0f)
#define H_C      (10.0f / 19.0f)
#define INV_H_C  (19.0f / 10.0f)

// pack two f32 -> bf16 pair (RNE), low = x, high = y  (intrinsic-only bit ops)
__device__ __forceinline__ unsigned int pk_bf16(float x, float y) {
    unsigned int ux = __float_as_uint(x); ux += 0x7FFFu + ((ux >> 16) & 1u);
    unsigned int uy = __float_as_uint(y); uy += 0x7FFFu + ((uy >> 16) & 1u);
    return (ux >> 16) | (uy & 0xFFFF0000u);
}
__device__ __forceinline__ float lo16(unsigned int u) { return __uint_as_float(u << 16); }
__device__ __forceinline__ float hi16(unsigned int u) { return __uint_as_float(u & 0xFFFF0000u); }

// ---------------------------------------------------------------------------
// Kernel 1: transpose + pack, SoA planes (bf16) — proven R6 structure.
//  coeffs [o=256][c=4864] float4 -> slice s = quarter*2 + o_half:
//    plane0[c_local*32 + og] = AB = {a01,a23,b01,b23}  (bf16 pairs over 4 o's)
//    plane1[c_local*32 + og] = CD = {c01,c23,d01,d23}
// ---------------------------------------------------------------------------
__global__ __launch_bounds__(256) void transpose_pack(
        const float4* __restrict__ src, uint4* __restrict__ dst) {
    __shared__ float4 tile[64][65];          // [c_local][o_local], +1 pad
    const int c0 = (blockIdx.x % 76) * 64;   // 1216 % 64 == 0: no quarter straddle
    const int r0 = (blockIdx.x / 76) * 64;
    const int tx = threadIdx.x & 63;
    const int ty = threadIdx.x >> 6;

    #pragma unroll
    for (int jj = 0; jj < 16; ++jj) {
        const int r = ty * 16 + jj;
        tile[tx][r] = src[(size_t)(r0 + r) * NCOL + (size_t)(c0 + tx)];
    }
    __syncthreads();

    const int quarter = c0 / CPQ;
    const int clbase  = c0 - quarter * CPQ;
    const int o_half  = r0 >> 7;
    const int og_base = (r0 & 127) >> 2;     // 0 or 16
    uint4* base = dst + (size_t)(quarter * 2 + o_half) * SLICE_U4;

    #pragma unroll
    for (int jj = 0; jj < 4; ++jj) {
        const int p  = jj * 256 + threadIdx.x;
        const int cl = p >> 4;
        const int og = p & 15;
        const float4 v0 = tile[cl][og * 4 + 0];
        const float4 v1 = tile[cl][og * 4 + 1];
        const float4 v2 = tile[cl][og * 4 + 2];
        const float4 v3 = tile[cl][og * 4 + 3];
        uint4 ab, cd;
        ab.x = pk_bf16(v0.x, v1.x); ab.y = pk_bf16(v2.x, v3.x);
        ab.z = pk_bf16(v0.y, v1.y); ab.w = pk_bf16(v2.y, v3.y);
        cd.x = pk_bf16(v0.z, v1.z); cd.y = pk_bf16(v2.z, v3.z);
        cd.z = pk_bf16(v0.w, v1.w); cd.w = pk_bf16(v2.w, v3.w);
        const size_t e = (size_t)(clbase + cl) * 32 + (og_base + og);
        base[e]            = ab;   // plane 0
        base[PLANE_U4 + e] = cd;   // plane 1
    }
}

// ---------------------------------------------------------------------------
// Kernel 2: partial gather+eval (R6 structure, unroll 8 for 2x loads in
//  flight). 256 thr = 8 bs x 32 og; thread owns 4 o's, 64 i's.
//  grid = 8 slices x 128 bgrps = 1024 blocks.
// ---------------------------------------------------------------------------
__global__ __launch_bounds__(256, 4) void kan_partial(
        const float* __restrict__ x,
        const uint4* __restrict__ Ct,
        float4*      __restrict__ part,     // [4][B][64] float4
        int n4q) {                          // B*64
    __shared__ int2 s_tk[8 * 64];           // .x = k*32 (plane elem offset), .y = t bits

    const int s       = blockIdx.x & 7;
    const int o_half  = s & 1;
    const int quarter = s >> 1;
    const int bgrp    = blockIdx.x >> 3;
    const int tid     = threadIdx.x;

    {
        const int col = tid & 63;
        const int row = tid >> 6;
        #pragma unroll
        for (int bs = row; bs < 8; bs += 4) {
            const float xv = x[(bgrp * 8 + bs) * IN_DIM + quarter * 64 + col];
            const float f  = (xv - X_MIN_C) * INV_H_C;
            int idx = (int)floorf(f);
            idx = idx < 0 ? 0 : (idx > NKNOT - 1 ? NKNOT - 1 : idx);
            s_tk[bs * 64 + col] =
                make_int2(idx * 32, __float_as_int(xv - (X_MIN_C + (float)idx * H_C)));
        }
    }
    __syncthreads();

    const int og = tid & 31;
    const int bs = tid >> 5;
    const uint4* baseAB = Ct + (size_t)s * SLICE_U4 + og;
    const uint4* baseCD = baseAB + PLANE_U4;
    const int2* tkp = s_tk + bs * 64;

    float y0 = 0.f, y1 = 0.f, y2 = 0.f, y3 = 0.f;

    #pragma unroll 8
    for (int ii = 0; ii < 64; ++ii) {
        const int2 tk = tkp[ii];
        const int  e  = ii * 608 + tk.x;     // (ii*19 + k) * 32
        const uint4 AB = baseAB[e];
        const uint4 CD = baseCD[e];
        const float t  = __int_as_float(tk.y);
        const float a_0 = lo16(AB.x), a_1 = hi16(AB.x), a_2 = lo16(AB.y), a_3 = hi16(AB.y);
        const float b_0 = lo16(AB.z), b_1 = hi16(AB.z), b_2 = lo16(AB.w), b_3 = hi16(AB.w);
        const float c_0 = lo16(CD.x), c_1 = hi16(CD.x), c_2 = lo16(CD.y), c_3 = hi16(CD.y);
        const float d_0 = lo16(CD.z), d_1 = hi16(CD.z), d_2 = lo16(CD.w), d_3 = hi16(CD.w);
        y0 += ((d_0 * t + c_0) * t + b_0) * t + a_0;
        y1 += ((d_1 * t + c_1) * t + b_1) * t + a_1;
        y2 += ((d_2 * t + c_2) * t + b_2) * t + a_2;
        y3 += ((d_3 * t + c_3) * t + b_3) * t + a_3;
    }

    const int b = bgrp * 8 + bs;
    part[(size_t)quarter * n4q + (size_t)b * 64 + (o_half * 32 + og)] =
        make_float4(y0, y1, y2, y3);
}

// ---------------------------------------------------------------------------
// Kernel 3: out = sum of 4 quarter-partials + bias  (float4)
// ---------------------------------------------------------------------------
__global__ __launch_bounds__(256) void kan_reduce(
        const float4* __restrict__ part,
        const float4* __restrict__ bias4,
        float4*       __restrict__ out,
        int n4) {
    const int n = blockIdx.x * 256 + threadIdx.x;
    if (n < n4) {
        const float4 p0 = part[n];
        const float4 p1 = part[n4 + n];
        const float4 p2 = part[2 * n4 + n];
        const float4 p3 = part[3 * n4 + n];
        const float4 bv = bias4[n & 63];
        float4 r;
        r.x = (p0.x + p1.x) + (p2.x + p3.x) + bv.x;
        r.y = (p0.y + p1.y) + (p2.y + p3.y) + bv.y;
        r.z = (p0.z + p1.z) + (p2.z + p3.z) + bv.z;
        r.w = (p0.w + p1.w) + (p2.w + p3.w) + bv.w;
        out[n] = r;
    }
}

// ---------------------------------------------------------------------------
extern "C" void kernel_launch(void* const* d_in, const int* in_sizes, int n_in,
                              void* d_out, int out_size, void* d_ws, size_t ws_size,
                              hipStream_t stream) {
    const float* x      = (const float*)d_in[0];   // (B, 256) fp32
    const float* coeffs = (const float*)d_in[1];   // (256, 256, 19, 4) fp32
    const float* bias   = (const float*)d_in[2];   // (256,) fp32
    float*       out    = (float*)d_out;           // (B, 256) fp32

    const int B = in_sizes[0] / IN_DIM;            // 1024
    uint4* Ct   = (uint4*)d_ws;                    // 9.96 MB
    float* part = (float*)((char*)d_ws + (16u << 20)); // 4 MB

    transpose_pack<<<304, 256, 0, stream>>>((const float4*)coeffs, Ct);

    const int n4 = B * OUT_DIM / 4;                // B*64
    kan_partial<<<B, 256, 0, stream>>>(x, Ct, (float4*)part, n4);
    kan_reduce<<<(n4 + 255) / 256, 256, 0, stream>>>(
        (const float4*)part, (const float4*)bias, (float4*)out, n4);
}

// Round 10
// 99.300 us; speedup vs baseline: 1.4534x; 1.0061x over previous
//
#include <hip/hip_runtime.h>

#define IN_DIM   256
#define OUT_DIM  256
#define NKNOT    19                    // NUM_KNOTS-1 spline segments
#define NCOL     (IN_DIM * NKNOT)      // 4864 (i,k) columns
#define CPQ      1216                  // columns per i-quarter (64*19)
#define PLANE_U4 (CPQ * 64)            // 77824 uint4 per plane (full o-dim)
#define SLICE_U4 (PLANE_U4 * 2)        // AB plane + CD plane per quarter
#define X_MIN_C  (-5.0f)
#define H_C      (10.0f / 19.0f)
#define INV_H_C  (19.0f / 10.0f)

// pack two f32 -> bf16 pair (RNE), low = x, high = y
__device__ __forceinline__ unsigned int pk_bf16(float x, float y) {
    unsigned int ux = __float_as_uint(x); ux += 0x7FFFu + ((ux >> 16) & 1u);
    unsigned int uy = __float_as_uint(y); uy += 0x7FFFu + ((uy >> 16) & 1u);
    return (ux >> 16) | (uy & 0xFFFF0000u);
}
__device__ __forceinline__ float lo16(unsigned int u) { return __uint_as_float(u << 16); }
__device__ __forceinline__ float hi16(unsigned int u) { return __uint_as_float(u & 0xFFFF0000u); }

// ---------------------------------------------------------------------------
// Kernel 1: transpose + pack, SoA planes (bf16), full-o rows.
//  coeffs [o=256][c=4864] float4 -> per-quarter slice:
//    plane0[c_local*64 + og] = AB = {a01,a23,b01,b23}  (og = o>>2, o-quad)
//    plane1[c_local*64 + og] = CD = {c01,c23,d01,d23}
//  A (c_local) row is 64 uint4 = 1 KB: one dense wave-load in the main kernel.
// ---------------------------------------------------------------------------
__global__ __launch_bounds__(256) void transpose_pack(
        const float4* __restrict__ src, uint4* __restrict__ dst) {
    __shared__ float4 tile[64][65];          // [c_local][o_local], +1 pad
    const int c0 = (blockIdx.x % 76) * 64;   // 1216 % 64 == 0: no quarter straddle
    const int r0 = (blockIdx.x / 76) * 64;
    const int tx = threadIdx.x & 63;
    const int ty = threadIdx.x >> 6;

    #pragma unroll
    for (int jj = 0; jj < 16; ++jj) {
        const int r = ty * 16 + jj;
        tile[tx][r] = src[(size_t)(r0 + r) * NCOL + (size_t)(c0 + tx)];
    }
    __syncthreads();

    const int quarter  = c0 / CPQ;
    const int clbase   = c0 - quarter * CPQ;
    const int og_base  = r0 >> 2;            // 0,16,32,48
    uint4* base = dst + (size_t)quarter * SLICE_U4;

    #pragma unroll
    for (int jj = 0; jj < 4; ++jj) {
        const int p  = jj * 256 + threadIdx.x;
        const int cl = p >> 4;
        const int og = p & 15;
        const float4 v0 = tile[cl][og * 4 + 0];
        const float4 v1 = tile[cl][og * 4 + 1];
        const float4 v2 = tile[cl][og * 4 + 2];
        const float4 v3 = tile[cl][og * 4 + 3];
        uint4 ab, cd;
        ab.x = pk_bf16(v0.x, v1.x); ab.y = pk_bf16(v2.x, v3.x);
        ab.z = pk_bf16(v0.y, v1.y); ab.w = pk_bf16(v2.y, v3.y);
        cd.x = pk_bf16(v0.z, v1.z); cd.y = pk_bf16(v2.z, v3.z);
        cd.z = pk_bf16(v0.w, v1.w); cd.w = pk_bf16(v2.w, v3.w);
        const size_t e = (size_t)(clbase + cl) * 64 + (og_base + og);
        base[e]            = ab;   // plane 0
        base[PLANE_U4 + e] = cd;   // plane 1
    }
}

// ---------------------------------------------------------------------------
// Kernel 2: tk precompute. tkg[b*256 + i] = {k, t bits} (int2).
// ---------------------------------------------------------------------------
__global__ __launch_bounds__(256) void make_tk(
        const float* __restrict__ x, int2* __restrict__ tkg, int Btot) {
    const int n = blockIdx.x * 256 + threadIdx.x;
    if (n >= Btot * IN_DIM) return;
    const float xv = x[n];
    int idx = (int)floorf((xv - X_MIN_C) * INV_H_C);
    idx = idx < 0 ? 0 : (idx > NKNOT - 1 ? NKNOT - 1 : idx);
    tkg[n] = make_int2(idx, __float_as_int(xv - (X_MIN_C + (float)idx * H_C)));
}

// ---------------------------------------------------------------------------
// Kernel 3: partial gather+eval — wave-uniform scalar-addressed gather.
//  grid = Btot blocks (4 quarters x Btot/4 bgrps); block = 4 waves.
//  Wave w owns batch row b = bgrp*4 + w and i-quarter q = blockIdx&3.
//  Lane = o-quad (o = lane*4 + j). Per i: k,t are wave-uniform (readlane ->
//  SGPR), coefficient load = SGPR base + lane*16 -> one dense 1KB segment.
//  No LDS, no barriers.
// ---------------------------------------------------------------------------
__global__ __launch_bounds__(256, 4) void kan_partial(
        const int2*  __restrict__ tkg,
        const uint4* __restrict__ Ct,
        float4*      __restrict__ part,     // [4][Btot][64] float4
        int Btot) {
    const int q    = blockIdx.x & 3;
    const int bgrp = blockIdx.x >> 2;
    const int w    = threadIdx.x >> 6;
    const int lane = threadIdx.x & 63;
    const int b    = bgrp * 4 + w;

    // lane i_l holds {k, t} for i = q*64 + i_l (coalesced 512B wave load)
    const int2 tkv = tkg[b * IN_DIM + q * 64 + lane];

    const char* baseAB = (const char*)(Ct + (size_t)q * SLICE_U4) + lane * 16;

    float y0 = 0.f, y1 = 0.f, y2 = 0.f, y3 = 0.f;

    #pragma unroll 4
    for (int ii = 0; ii < 64; ++ii) {
        const int   k = __builtin_amdgcn_readlane(tkv.x, ii);           // SGPR
        const float t = __uint_as_float(
            (unsigned int)__builtin_amdgcn_readlane(tkv.y, ii));        // SGPR
        const size_t off = (size_t)(ii * NKNOT + k) * 1024;             // scalar
        const uint4 AB = *(const uint4*)(baseAB + off);
        const uint4 CD = *(const uint4*)(baseAB + (size_t)PLANE_U4 * 16 + off);
        const float a_0 = lo16(AB.x), a_1 = hi16(AB.x), a_2 = lo16(AB.y), a_3 = hi16(AB.y);
        const float b_0 = lo16(AB.z), b_1 = hi16(AB.z), b_2 = lo16(AB.w), b_3 = hi16(AB.w);
        const float c_0 = lo16(CD.x), c_1 = hi16(CD.x), c_2 = lo16(CD.y), c_3 = hi16(CD.y);
        const float d_0 = lo16(CD.z), d_1 = hi16(CD.z), d_2 = lo16(CD.w), d_3 = hi16(CD.w);
        y0 += ((d_0 * t + c_0) * t + b_0) * t + a_0;
        y1 += ((d_1 * t + c_1) * t + b_1) * t + a_1;
        y2 += ((d_2 * t + c_2) * t + b_2) * t + a_2;
        y3 += ((d_3 * t + c_3) * t + b_3) * t + a_3;
    }

    // o = lane*4 + j ; float4-index = b*64 + lane  (1KB coalesced per wave)
    part[((size_t)q * Btot + b) * 64 + lane] = make_float4(y0, y1, y2, y3);
}

// ---------------------------------------------------------------------------
// Kernel 4: out = sum of 4 quarter-partials + bias  (float4)
// ---------------------------------------------------------------------------
__global__ __launch_bounds__(256) void kan_reduce(
        const float4* __restrict__ part,
        const float4* __restrict__ bias4,  // [64]
        float4*       __restrict__ out,
        int n4) {
    const int n = blockIdx.x * 256 + threadIdx.x;
    if (n < n4) {
        const float4 p0 = part[n];
        const float4 p1 = part[n4 + n];
        const float4 p2 = part[2 * n4 + n];
        const float4 p3 = part[3 * n4 + n];
        const float4 bv = bias4[n & 63];
        float4 r;
        r.x = (p0.x + p1.x) + (p2.x + p3.x) + bv.x;
        r.y = (p0.y + p1.y) + (p2.y + p3.y) + bv.y;
        r.z = (p0.z + p1.z) + (p2.z + p3.z) + bv.z;
        r.w = (p0.w + p1.w) + (p2.w + p3.w) + bv.w;
        out[n] = r;
    }
}

// ---------------------------------------------------------------------------
extern "C" void kernel_launch(void* const* d_in, const int* in_sizes, int n_in,
                              void* d_out, int out_size, void* d_ws, size_t ws_size,
                              hipStream_t stream) {
    const float* x      = (const float*)d_in[0];   // (B, 256) fp32
    const float* coeffs = (const float*)d_in[1];   // (256, 256, 19, 4) fp32
    const float* bias   = (const float*)d_in[2];   // (256,) fp32
    float*       out    = (float*)d_out;           // (B, 256) fp32

    const int B = in_sizes[0] / IN_DIM;            // 1024
    uint4* Ct   = (uint4*)d_ws;                            // 9.96 MB
    int2*  tkg  = (int2*)((char*)d_ws + (12u << 20));      // 2 MB
    float* part = (float*)((char*)d_ws + (16u << 20));     // 4 MB

    transpose_pack<<<304, 256, 0, stream>>>((const float4*)coeffs, Ct);
    make_tk<<<(B * IN_DIM + 255) / 256, 256, 0, stream>>>(x, tkg, B);
    kan_partial<<<B, 256, 0, stream>>>(tkg, Ct, (float4*)part, B);

    const int n4 = B * OUT_DIM / 4;                // B*64
    kan_reduce<<<(n4 + 255) / 256, 256, 0, stream>>>(
        (const float4*)part, (const float4*)bias, (float4*)out, n4);
}